// Round 1
// baseline (2453.508 us; speedup 1.0000x reference)
//
#include <hip/hip_runtime.h>
#include <math.h>

// Problem constants
#define B_ 16
#define C_ 64
#define H_ 128
#define W_ 128
#define HW_ (H_*W_)
#define OUT_ELEMS 16777216   // B*C*H*W

// Workspace layout (in floats). Total = 274944 + 2*16777216 floats ~= 129.1 MiB
#define CHM_OFF   0           // ch_mask: 512
#define WCT_OFF   512         // transposed wc: [256][64] = 16384
#define WT_OFF    16896       // 7 weight sets, each [576][64] = 36864
#define WT_SET    36864
#define FEA_A_OFF 274944
#define FEA_B_OFF (274944 + OUT_ELEMS)

// ---------------------------------------------------------------------------
// ch_mask = softmax((param + (-log(-log(u))))/tau, axis=-1), tau=1, last dim 2
__global__ __launch_bounds__(64) void mask_kernel(
    const float* __restrict__ gum, const float* __restrict__ par,
    float* __restrict__ chm, float* __restrict__ out_tail)
{
    int c = threadIdx.x;  // 0..63
    #pragma unroll
    for (int i = 0; i < 4; ++i) {
        int base = (c*4 + i)*2;
        float g0 = -logf(-logf(gum[base]));
        float g1 = -logf(-logf(gum[base+1]));
        float a0 = par[base] + g0, a1 = par[base+1] + g1;
        float mx = fmaxf(a0, a1);
        float e0 = expf(a0 - mx), e1 = expf(a1 - mx);
        float inv = 1.0f / (e0 + e1);
        float m0 = e0*inv, m1 = e1*inv;
        chm[base] = m0; chm[base+1] = m1;
        out_tail[base] = m0; out_tail[base+1] = m1;
    }
}

// ---------------------------------------------------------------------------
// Build transposed (+gate-scaled) weights:
//   wt_all[set][k][o],  k = ic*9 + ky*3 + kx, set: 0=w0 plain,
//   1/2 = w1*md1 / w1*ms1, 3/4 = w2*md2/ms2, 5/6 = w3*md3/ms3
// and wct[row][o] = wc[o][row], row = stage*64 + c.
__global__ __launch_bounds__(256) void prep_kernel(
    const float* __restrict__ w0, const float* __restrict__ w1,
    const float* __restrict__ w2, const float* __restrict__ w3,
    const float* __restrict__ wc, const float* __restrict__ chm,
    float* __restrict__ wt_all, float* __restrict__ wct)
{
    int idx = blockIdx.x*256 + threadIdx.x;
    if (idx < 7*WT_SET) {
        int set = idx / WT_SET;
        int r   = idx % WT_SET;
        int k   = r >> 6;     // 0..575
        int o   = r & 63;
        int ic  = k / 9;
        int k9  = k % 9;
        const float* wsrc = (set == 0) ? w0 : (set <= 2 ? w1 : (set <= 4 ? w2 : w3));
        float v = wsrc[(o*64 + ic)*9 + k9];
        if (set > 0) {
            int stage = (set + 1) >> 1;   // 1,1,2,2,3,3
            int sel   = (set - 1) & 1;    // 0=dense,1=sparse
            v *= chm[(ic*4 + stage)*2 + sel];
        }
        wt_all[idx] = v;   // idx == set*WT_SET + k*64 + o
    } else {
        int r2 = idx - 7*WT_SET;
        if (r2 < 256*64) {
            int row = r2 >> 6; int o = r2 & 63;
            wct[row*64 + o] = wc[o*256 + row];
        }
    }
}

// ---------------------------------------------------------------------------
// Direct 3x3 conv, SAME padding. Block tile: 64 oc x 64 px (one row segment).
// 256 threads: 16 oc-groups x 16 px-groups; each thread 4 oc x 4 px.
// DUAL: two weight sets (dense/sparse scaled) accumulated in one input pass.
// Epilogue: fea = relu(A*(ms*spa+md) [+ S*(ms+md)*spa]) using OUTPUT-channel gates.
template<bool DUAL>
__global__ __launch_bounds__(256) void conv_kernel(
    const float* __restrict__ in, const float* __restrict__ wtA,
    const float* __restrict__ wtS, const float* __restrict__ chm,
    const float* __restrict__ spa, float* __restrict__ outFea, int stage)
{
    __shared__ float s_in[8*3*68];            // 8 ic x 3 rows x 66 cols (stride 68)
    __shared__ float s_wA[8*9*64];
    __shared__ float s_wS[DUAL ? 8*9*64 : 4];

    const int tid = threadIdx.x;
    const int bid = blockIdx.x;
    const int w0 = (bid & 1) * 64;
    const int h  = (bid >> 1) & 127;
    const int b  = bid >> 8;
    const int oc0 = (tid >> 4) * 4;
    const int px0 = (tid & 15) * 4;

    float accA[4][4] = {{0.f}};
    float accS[4][4] = {{0.f}};

    for (int ch = 0; ch < 8; ++ch) {
        const int ic0 = ch * 8;
        __syncthreads();
        // stage input rows (zero-padded halo)
        for (int e = tid; e < 8*3*66; e += 256) {
            int ici = e / 198;
            int rem = e - ici*198;
            int ky  = rem / 66;
            int cc  = rem - ky*66;
            int gh  = h + ky - 1;
            int gw  = w0 - 1 + cc;
            float v = 0.f;
            if ((unsigned)gh < (unsigned)H_ && (unsigned)gw < (unsigned)W_)
                v = in[((b*C_ + ic0 + ici)*H_ + gh)*W_ + gw];
            s_in[(ici*3 + ky)*68 + cc] = v;
        }
        // stage weights (contiguous, float4)
        {
            const float4* srcA = (const float4*)(wtA + ic0*576);
            float4* dstA = (float4*)s_wA;
            for (int v4 = tid; v4 < 1152; v4 += 256) dstA[v4] = srcA[v4];
            if (DUAL) {
                const float4* srcS = (const float4*)(wtS + ic0*576);
                float4* dstS = (float4*)s_wS;
                for (int v4 = tid; v4 < 1152; v4 += 256) dstS[v4] = srcS[v4];
            }
        }
        __syncthreads();

        for (int i = 0; i < 8; ++i) {
            #pragma unroll
            for (int ky = 0; ky < 3; ++ky) {
                const float* rowp = &s_in[(i*3 + ky)*68 + px0];
                float4 v0 = *(const float4*)rowp;
                float2 v1 = *(const float2*)(rowp + 4);
                float vals[6] = {v0.x, v0.y, v0.z, v0.w, v1.x, v1.y};
                #pragma unroll
                for (int kx = 0; kx < 3; ++kx) {
                    const float4 wA = *(const float4*)&s_wA[(i*9 + ky*3 + kx)*64 + oc0];
                    float4 wS;
                    if (DUAL) wS = *(const float4*)&s_wS[(i*9 + ky*3 + kx)*64 + oc0];
                    #pragma unroll
                    for (int p = 0; p < 4; ++p) {
                        float xv = vals[kx + p];
                        accA[0][p] += wA.x * xv;
                        accA[1][p] += wA.y * xv;
                        accA[2][p] += wA.z * xv;
                        accA[3][p] += wA.w * xv;
                        if (DUAL) {
                            accS[0][p] += wS.x * xv;
                            accS[1][p] += wS.y * xv;
                            accS[2][p] += wS.z * xv;
                            accS[3][p] += wS.w * xv;
                        }
                    }
                }
            }
        }
    }

    // epilogue: gating + relu
    float4 spav = *(const float4*)&spa[b*HW_ + h*W_ + w0 + px0];
    float spaa[4] = {spav.x, spav.y, spav.z, spav.w};
    #pragma unroll
    for (int o = 0; o < 4; ++o) {
        int oc = oc0 + o;
        float md = chm[(oc*4 + stage)*2 + 0];
        float ms = chm[(oc*4 + stage)*2 + 1];
        float4 r;
        float* rr = (float*)&r;
        #pragma unroll
        for (int p = 0; p < 4; ++p) {
            float f = accA[o][p] * (ms*spaa[p] + md);
            if (DUAL) f += accS[o][p] * ((ms + md)*spaa[p]);
            rr[p] = fmaxf(f, 0.f);
        }
        *(float4*)&outFea[((b*C_ + oc)*H_ + h)*W_ + w0 + px0] = r;
    }
}

// ---------------------------------------------------------------------------
// Pointwise 64->64 GEMM for one stage's contribution to out.
// out[b,o,p] (+)= sum_c wct[stage*64+c][o] * fea[b,c,p]  (+ bc[o] if first)
__global__ __launch_bounds__(256) void pw_kernel(
    const float* __restrict__ fea, const float* __restrict__ wslice,
    const float* __restrict__ bc, float* __restrict__ out, int first)
{
    __shared__ float s_w[64*64];
    __shared__ float s_f[64*64];
    const int tid = threadIdx.x;
    const int bid = blockIdx.x;
    const int w0 = (bid & 1) * 64;
    const int h  = (bid >> 1) & 127;
    const int b  = bid >> 8;
    const int oc0 = (tid >> 4) * 4;
    const int px0 = (tid & 15) * 4;

    for (int v4 = tid; v4 < 1024; v4 += 256)
        ((float4*)s_w)[v4] = ((const float4*)wslice)[v4];
    {
        const int base = b*C_*HW_ + h*W_ + w0;
        for (int v4 = tid; v4 < 1024; v4 += 256) {
            int c = v4 >> 4; int w4 = v4 & 15;
            ((float4*)s_f)[v4] = *(const float4*)&fea[base + c*HW_ + w4*4];
        }
    }
    __syncthreads();

    float acc[4][4] = {{0.f}};
    #pragma unroll 4
    for (int c = 0; c < 64; ++c) {
        float4 wv = *(const float4*)&s_w[c*64 + oc0];
        float4 xv = *(const float4*)&s_f[c*64 + px0];
        const float xs[4]  = {xv.x, xv.y, xv.z, xv.w};
        const float wsv[4] = {wv.x, wv.y, wv.z, wv.w};
        #pragma unroll
        for (int o = 0; o < 4; ++o)
            #pragma unroll
            for (int p = 0; p < 4; ++p)
                acc[o][p] += wsv[o]*xs[p];
    }

    #pragma unroll
    for (int o = 0; o < 4; ++o) {
        int oc = oc0 + o;
        float* op = &out[((b*C_ + oc)*H_ + h)*W_ + w0 + px0];
        float4 r;
        if (first) {
            float bias = bc[oc];
            r.x = acc[o][0]+bias; r.y = acc[o][1]+bias;
            r.z = acc[o][2]+bias; r.w = acc[o][3]+bias;
        } else {
            float4 prev = *(const float4*)op;
            r.x = prev.x+acc[o][0]; r.y = prev.y+acc[o][1];
            r.z = prev.z+acc[o][2]; r.w = prev.w+acc[o][3];
        }
        *(float4*)op = r;
    }
}

// ---------------------------------------------------------------------------
extern "C" void kernel_launch(void* const* d_in, const int* in_sizes, int n_in,
                              void* d_out, int out_size, void* d_ws, size_t ws_size,
                              hipStream_t stream)
{
    const float* x0  = (const float*)d_in[0];
    const float* spa = (const float*)d_in[1];
    const float* gum = (const float*)d_in[2];
    const float* par = (const float*)d_in[3];
    const float* w0  = (const float*)d_in[4];
    const float* w1  = (const float*)d_in[5];
    const float* w2  = (const float*)d_in[6];
    const float* w3  = (const float*)d_in[7];
    const float* wc  = (const float*)d_in[8];
    const float* bc  = (const float*)d_in[9];
    float* out = (float*)d_out;
    float* ws  = (float*)d_ws;

    float* chm  = ws + CHM_OFF;
    float* wct  = ws + WCT_OFF;
    float* wt   = ws + WT_OFF;
    float* feaA = ws + FEA_A_OFF;
    float* feaB = ws + FEA_B_OFF;

    mask_kernel<<<1, 64, 0, stream>>>(gum, par, chm, out + OUT_ELEMS);
    prep_kernel<<<1072, 256, 0, stream>>>(w0, w1, w2, w3, wc, chm, wt, wct);

    // stage 0: single conv of x0
    conv_kernel<false><<<4096, 256, 0, stream>>>(x0, wt, nullptr, chm, spa, feaA, 0);
    pw_kernel<<<4096, 256, 0, stream>>>(feaA, wct + 0*4096, bc, out, 1);

    // stage 1
    conv_kernel<true><<<4096, 256, 0, stream>>>(feaA, wt + 1*WT_SET, wt + 2*WT_SET, chm, spa, feaB, 1);
    pw_kernel<<<4096, 256, 0, stream>>>(feaB, wct + 1*4096, bc, out, 0);

    // stage 2
    conv_kernel<true><<<4096, 256, 0, stream>>>(feaB, wt + 3*WT_SET, wt + 4*WT_SET, chm, spa, feaA, 2);
    pw_kernel<<<4096, 256, 0, stream>>>(feaA, wct + 2*4096, bc, out, 0);

    // stage 3
    conv_kernel<true><<<4096, 256, 0, stream>>>(feaA, wt + 5*WT_SET, wt + 6*WT_SET, chm, spa, feaB, 3);
    pw_kernel<<<4096, 256, 0, stream>>>(feaB, wct + 3*4096, bc, out, 0);
}